// Round 9
// baseline (450.744 us; speedup 1.0000x reference)
//
#include <hip/hip_runtime.h>
#include <hip/hip_fp16.h>

// Problem constants (B=1 fixed)
#define CC   32
#define DD   24
#define HH   96
#define WW   96
#define HWC  (HH*WW)        // 9216
#define DHW  (DD*HH*WW)     // 221184
#define NG   4
#define CPG  (CC/NG)        // 8
#define OC1  54
#define GN_EPS 1e-5f

// halo-padded activation tensor: [D][98][98][32] f16
#define WP   98
#define PLP  (WP*WP)        // 9604
#define NHP  (DD*PLP*CC)    // padded halves total

#define NBLK_F (DHW/64)     // 3456 fused blocks (64 pts, 2 waves x 32 pts)
#define CHUNK_F (NBLK_F/8)  // 432
#define NBLK_G (DHW/256)    // 864  (gn_apply)
#define CHUNK_G (NBLK_G/8)  // 108

typedef float  f32x4 __attribute__((ext_vector_type(4)));
typedef _Float16 f16x8 __attribute__((ext_vector_type(8)));
typedef unsigned int u32x4 __attribute__((ext_vector_type(4)));

union F16Frag { f16x8 v; __half2 h2[4]; };

// XCD-chunked swizzle: block b -> XCD b%8 gets a contiguous chunk, so every
// kernel's XCD k owns the SAME 27648-point slice (producer/consumer L2 match).
__device__ __forceinline__ int swz(int bid, int chunk) {
    return (bid % 8) * chunk + (bid / 8);
}

// ---- pack weights into per-tap MFMA B-fragments ----
// src: [O][CC][27] fp32. dst: [tap][nt][lane][e] f16, o=nt*16+(lane&15), c=(lane>>4)*8+e.
__global__ void pack_w(const float* __restrict__ src, _Float16* __restrict__ dst,
                       int O, int NT, int n) {
    int idx = blockIdx.x * 256 + threadIdx.x;
    if (idx >= n) return;
    int e    = idx & 7;
    int lane = (idx >> 3) & 63;
    int nt   = (idx >> 9) % NT;
    int tap  = (idx >> 9) / NT;
    int o = nt * 16 + (lane & 15);
    int c = (lane >> 4) * 8 + e;
    float v = (o < O) ? src[(o * CC + c) * 27 + tap] : 0.f;
    dst[idx] = (_Float16)v;
}

// ---- group-norm stats ----
__global__ void gn_stats(const float* __restrict__ x, float* __restrict__ stats) {
    const int g = blockIdx.x >> 5;
    const int s = blockIdx.x & 31;
    const float4* base = (const float4*)(x + (size_t)g * CPG * DHW);
    const int n4 = CPG * DHW / 4;
    float s1 = 0.f, s2 = 0.f;
    for (int idx = s * 256 + threadIdx.x; idx < n4; idx += 32 * 256) {
        float4 v = base[idx];
        s1 += v.x + v.y + v.z + v.w;
        s2 += v.x * v.x + v.y * v.y + v.z * v.z + v.w * v.w;
    }
    for (int off = 32; off > 0; off >>= 1) {
        s1 += __shfl_down(s1, off);
        s2 += __shfl_down(s2, off);
    }
    __shared__ float ls1[4], ls2[4];
    int wid = threadIdx.x >> 6;
    if ((threadIdx.x & 63) == 0) { ls1[wid] = s1; ls2[wid] = s2; }
    __syncthreads();
    if (threadIdx.x == 0) {
        float a = 0.f, b = 0.f;
        for (int i = 0; i < 4; i++) { a += ls1[i]; b += ls2[i]; }
        atomicAdd(&stats[g * 2 + 0], a);
        atomicAdd(&stats[g * 2 + 1], b);
    }
}

// ---- group-norm apply + relu + transpose to halo-padded channels-last f16 ----
__global__ void gn_apply_T(const float* __restrict__ x, const float* __restrict__ stats,
                           const float* __restrict__ gamma, const float* __restrict__ beta,
                           __half* __restrict__ yTp) {
    const int p = swz(blockIdx.x, CHUNK_G) * 256 + threadIdx.x;
    const float invN = 1.0f / (float)(CPG * DHW);
    float mean[NG], rstd[NG];
#pragma unroll
    for (int g = 0; g < NG; g++) {
        mean[g] = stats[2 * g] * invN;
        float var = stats[2 * g + 1] * invN - mean[g] * mean[g];
        rstd[g] = rsqrtf(var + GN_EPS);
    }
    float vals[CC];
#pragma unroll
    for (int c = 0; c < CC; c++) {
        const int g = c >> 3;
        const float ga = gamma[c] * rstd[g];
        const float be = beta[c] - mean[g] * ga;
        vals[c] = fmaxf(0.f, x[(size_t)c * DHW + p] * ga + be);
    }
    union { __half2 h2[16]; u32x4 q[4]; } u;
#pragma unroll
    for (int c = 0; c < 16; c++) u.h2[c] = __floats2half2_rn(vals[2 * c], vals[2 * c + 1]);
    const int d = p / HWC;
    const int rr = p % HWC;
    const int h = rr / WW;
    const int w = rr % WW;
    u32x4* dst = (u32x4*)(yTp + ((size_t)d * PLP + (size_t)(h + 1) * WP + (w + 1)) * CC);
#pragma unroll
    for (int q = 0; q < 4; q++) dst[q] = u.q[q];
}

// ---- FUSED: offset conv (32->54, MFMA) -> LDS -> deformable conv (MFMA) ----
// Per block: 64 points, 2 waves, each wave owns 32 points (m-tiles 0..1).
// Verified C/D mapping: o(col) = nt*16 + (lane&15), point(row) = m*16 + (lane>>4)*4 + reg.
#define OPAD 34   // halves per offset row (32 pts + 2 pad)
__global__ __launch_bounds__(128, 6) void fused_conv(const __half* __restrict__ xTp,
                                                     const _Float16* __restrict__ wBo,
                                                     const float* __restrict__ ob,
                                                     const _Float16* __restrict__ wBd,
                                                     const float* __restrict__ db,
                                                     const float* __restrict__ resid,
                                                     float* __restrict__ outp) {
    __shared__ __align__(16) char lds_raw[CC * 68 * 4];   // 8704 B (>= 2*54*34*2 = 7344)
    __half* offs_lds = (__half*)lds_raw;
    float*  out_lds  = (float*)lds_raw;

    const int tid  = threadIdx.x;
    const int lane = tid & 63;
    const int wave = tid >> 6;
    const int p0   = swz(blockIdx.x, CHUNK_F) * 64;
    const int pw   = p0 + wave * 32;
    const int d    = pw / HWC;        // 64 | 9216: no d-crossing in a block
    const int rem  = pw % HWC;
    const int mrow = lane & 15;
    const int kg   = lane >> 4;
    const int wbase = wave * (OC1 * OPAD);

    int hq[2], wq[2];
#pragma unroll
    for (int m = 0; m < 2; m++) {
        int rr = rem + m * 16 + mrow;
        hq[m] = rr / WW; wq[m] = rr % WW;
    }

    // ================= Phase A: offset conv (halo-padded, unconditional loads) ====
    f32x4 aco[2][4];
#pragma unroll
    for (int m = 0; m < 2; m++)
#pragma unroll
        for (int n = 0; n < 4; n++) aco[m][n] = (f32x4){0.f, 0.f, 0.f, 0.f};

    const f16x8* wbo8 = (const f16x8*)wBo;

#pragma unroll 1
    for (int i = 0; i < 3; i++) {
        const int dd = d + i - 1;
        if ((unsigned)dd >= DD) continue;
        const __half* xd = xTp + (size_t)dd * PLP * CC;
#pragma unroll 3
        for (int jk = 0; jk < 9; jk++) {
            const int j = jk / 3, k = jk % 3, tap = i * 9 + jk;
            const f16x8 b0 = wbo8[(tap * 4 + 0) * 64 + lane];
            const f16x8 b1 = wbo8[(tap * 4 + 1) * 64 + lane];
            const f16x8 b2 = wbo8[(tap * 4 + 2) * 64 + lane];
            const f16x8 b3 = wbo8[(tap * 4 + 3) * 64 + lane];
            f16x8 a[2];
#pragma unroll
            for (int m = 0; m < 2; m++)
                a[m] = *(const f16x8*)(xd + (size_t)((hq[m] + j) * WP + wq[m] + k) * CC + kg * 8);
#pragma unroll
            for (int m = 0; m < 2; m++) {
                aco[m][0] = __builtin_amdgcn_mfma_f32_16x16x32_f16(a[m], b0, aco[m][0], 0, 0, 0);
                aco[m][1] = __builtin_amdgcn_mfma_f32_16x16x32_f16(a[m], b1, aco[m][1], 0, 0, 0);
                aco[m][2] = __builtin_amdgcn_mfma_f32_16x16x32_f16(a[m], b2, aco[m][2], 0, 0, 0);
                aco[m][3] = __builtin_amdgcn_mfma_f32_16x16x32_f16(a[m], b3, aco[m][3], 0, 0, 0);
            }
        }
    }

    // ================= Phase B: stage offsets in LDS (o-major, +bias) ======
    float bo[4];
#pragma unroll
    for (int nt = 0; nt < 4; nt++) {
        const int o = nt * 16 + mrow;
        bo[nt] = (o < OC1) ? ob[o] : 0.f;
    }
#pragma unroll
    for (int m = 0; m < 2; m++) {
#pragma unroll
        for (int nt = 0; nt < 4; nt++) {
            const int o = nt * 16 + mrow;
            if (o < OC1) {
                const int idx = wbase + o * OPAD + m * 16 + kg * 4;
                __half2 lo = __floats2half2_rn(aco[m][nt].x + bo[nt], aco[m][nt].y + bo[nt]);
                __half2 hi = __floats2half2_rn(aco[m][nt].z + bo[nt], aco[m][nt].w + bo[nt]);
                *(__half2*)&offs_lds[idx]     = lo;
                *(__half2*)&offs_lds[idx + 2] = hi;
            }
        }
    }
    __syncthreads();

    // ================= Phase C: deformable conv =================
    f32x4 acd[2][2];
#pragma unroll
    for (int m = 0; m < 2; m++) {
        acd[m][0] = (f32x4){0.f, 0.f, 0.f, 0.f};
        acd[m][1] = (f32x4){0.f, 0.f, 0.f, 0.f};
    }

    const f16x8* wbd8 = (const f16x8*)wBd;

#pragma unroll 1
    for (int i = 0; i < 3; i++) {
        const int dd = d + i - 1;
        if ((unsigned)dd >= DD) continue;   // zero-padded depth
        const __half* xd = xTp + (size_t)dd * PLP * CC;
#pragma unroll 3
        for (int jk = 0; jk < 9; jk++) {
            const int j = jk / 3, k = jk % 3, tap = i * 9 + jk;
            const f16x8 b0 = wbd8[(tap * 2 + 0) * 64 + lane];
            const f16x8 b1 = wbd8[(tap * 2 + 1) * 64 + lane];
            // batch 1: offsets (LDS) -> addresses + coeffs for both m
            int i00[2], i01[2], i10[2], i11[2];
            float c00[2], c01[2], c10[2], c11[2];
#pragma unroll
            for (int m = 0; m < 2; m++) {
                const int ptl = m * 16 + mrow;
                const float oh = __half2float(offs_lds[wbase + (2 * tap + 0) * OPAD + ptl]);
                const float ov = __half2float(offs_lds[wbase + (2 * tap + 1) * OPAD + ptl]);
                const float hp  = (float)(hq[m] + j - 1) + oh;
                const float wpf = (float)(wq[m] + k - 1) + ov;
                const float h0f = floorf(hp), w0f = floorf(wpf);
                const int h0 = (int)h0f, w0 = (int)w0f;
                const float lh = hp - h0f, lw = wpf - w0f;
                const bool hv0 = (h0 >= 0) && (h0 < HH);
                const bool hv1 = (h0 >= -1) && (h0 < HH - 1);
                const bool wv0 = (w0 >= 0) && (w0 < WW);
                const bool wv1 = (w0 >= -1) && (w0 < WW - 1);
                c00[m] = (hv0 && wv0) ? (1.f - lh) * (1.f - lw) : 0.f;
                c01[m] = (hv0 && wv1) ? (1.f - lh) * lw : 0.f;
                c10[m] = (hv1 && wv0) ? lh * (1.f - lw) : 0.f;
                c11[m] = (hv1 && wv1) ? lh * lw : 0.f;
                const int h0c = min(max(h0, 0), HH - 1) + 1;
                const int h1c = min(max(h0 + 1, 0), HH - 1) + 1;
                const int w0c = min(max(w0, 0), WW - 1) + 1;
                const int w1c = min(max(w0 + 1, 0), WW - 1) + 1;
                i00[m] = h0c * WP + w0c;
                i01[m] = h0c * WP + w1c;
                i10[m] = h1c * WP + w0c;
                i11[m] = h1c * WP + w1c;
            }
            // batch 2: gathers + blend + MFMA
#pragma unroll
            for (int m = 0; m < 2; m++) {
                F16Frag a00, a01, a10, a11, A;
                a00.v = *(const f16x8*)(xd + (size_t)i00[m] * CC + kg * 8);
                a01.v = *(const f16x8*)(xd + (size_t)i01[m] * CC + kg * 8);
                a10.v = *(const f16x8*)(xd + (size_t)i10[m] * CC + kg * 8);
                a11.v = *(const f16x8*)(xd + (size_t)i11[m] * CC + kg * 8);
                const __half2 C00 = __float2half2_rn(c00[m]);
                const __half2 C01 = __float2half2_rn(c01[m]);
                const __half2 C10 = __float2half2_rn(c10[m]);
                const __half2 C11 = __float2half2_rn(c11[m]);
#pragma unroll
                for (int r = 0; r < 4; r++) {
                    __half2 t = __hmul2(C00, a00.h2[r]);
                    t = __hfma2(C01, a01.h2[r], t);
                    t = __hfma2(C10, a10.h2[r], t);
                    t = __hfma2(C11, a11.h2[r], t);
                    A.h2[r] = t;
                }
                acd[m][0] = __builtin_amdgcn_mfma_f32_16x16x32_f16(A.v, b0, acd[m][0], 0, 0, 0);
                acd[m][1] = __builtin_amdgcn_mfma_f32_16x16x32_f16(A.v, b1, acd[m][1], 0, 0, 0);
            }
        }
    }
    __syncthreads();   // offsets dead; reuse LDS for output staging

    // ================= Phase D: stage + coalesced copy-out =================
#pragma unroll
    for (int m = 0; m < 2; m++)
#pragma unroll
        for (int nt = 0; nt < 2; nt++) {
            const int o = nt * 16 + mrow;
            *(f32x4*)&out_lds[o * 68 + wave * 32 + m * 16 + kg * 4] = acd[m][nt];
        }
    __syncthreads();
    // copy out: 128 threads = 64 pts x 2 o-halves
    const int pp = tid & 63;
    const int obh = tid >> 6;
    if (resid) {
#pragma unroll
        for (int o2 = 0; o2 < 16; o2++) {
            const int o = o2 * 2 + obh;
            float v = out_lds[o * 68 + pp] + db[o] + resid[(size_t)o * DHW + p0 + pp];
            outp[(size_t)o * DHW + p0 + pp] = v;
        }
    } else {
#pragma unroll
        for (int o2 = 0; o2 < 16; o2++) {
            const int o = o2 * 2 + obh;
            outp[(size_t)o * DHW + p0 + pp] = out_lds[o * 68 + pp] + db[o];
        }
    }
}

extern "C" void kernel_launch(void* const* d_in, const int* in_sizes, int n_in,
                              void* d_out, int out_size, void* d_ws, size_t ws_size,
                              hipStream_t stream) {
    const float* x   = (const float*)d_in[0];
    const float* g1  = (const float*)d_in[1];
    const float* be1 = (const float*)d_in[2];
    const float* g2  = (const float*)d_in[3];
    const float* be2 = (const float*)d_in[4];
    const float* ow1 = (const float*)d_in[5];
    const float* ob1 = (const float*)d_in[6];
    const float* dw1 = (const float*)d_in[7];
    const float* db1 = (const float*)d_in[8];
    const float* ow2 = (const float*)d_in[9];
    const float* ob2 = (const float*)d_in[10];
    const float* dw2 = (const float*)d_in[11];
    const float* db2 = (const float*)d_in[12];
    float* out = (float*)d_out;
    float* ws  = (float*)d_ws;

    // ws layout (float offsets)
    float*    stats = ws;                           // 16
    _Float16* wBo1  = (_Float16*)(ws + 256);        // 55296 h = 27648 f
    _Float16* wBd1  = (_Float16*)(ws + 27904);      // 27648 h = 13824 f
    _Float16* wBo2  = (_Float16*)(ws + 41728);      // 27648 f
    _Float16* wBd2  = (_Float16*)(ws + 69376);      // 13824 f
    __half*   hTp   = (__half*)(ws + 83200);        // padded: 24*9604*32 h = 3,687,936 f

    (void)hipMemsetAsync(stats, 0, 16 * sizeof(float), stream);
    (void)hipMemsetAsync(hTp, 0, (size_t)NHP * sizeof(__half), stream);  // zero halo (+interior, overwritten)
    pack_w<<<(27 * 4 * 512 + 255) / 256, 256, 0, stream>>>(ow1, wBo1, 54, 4, 27 * 4 * 512);
    pack_w<<<(27 * 2 * 512 + 255) / 256, 256, 0, stream>>>(dw1, wBd1, 32, 2, 27 * 2 * 512);
    pack_w<<<(27 * 4 * 512 + 255) / 256, 256, 0, stream>>>(ow2, wBo2, 54, 4, 27 * 4 * 512);
    pack_w<<<(27 * 2 * 512 + 255) / 256, 256, 0, stream>>>(dw2, wBd2, 32, 2, 27 * 2 * 512);

    // block 1
    gn_stats<<<NG * 32, 256, 0, stream>>>(x, stats + 0);
    gn_apply_T<<<NBLK_G, 256, 0, stream>>>(x, stats + 0, g1, be1, hTp);
    fused_conv<<<NBLK_F, 128, 0, stream>>>(hTp, wBo1, ob1, wBd1, db1, nullptr, out);

    // block 2 (input = block-1 output in d_out; halo stays zero)
    gn_stats<<<NG * 32, 256, 0, stream>>>(out, stats + 8);
    gn_apply_T<<<NBLK_G, 256, 0, stream>>>(out, stats + 8, g2, be2, hTp);
    fused_conv<<<NBLK_F, 128, 0, stream>>>(hTp, wBo2, ob2, wBd2, db2, x, out);
}

// Round 10
// 430.452 us; speedup vs baseline: 1.0471x; 1.0471x over previous
//
#include <hip/hip_runtime.h>
#include <hip/hip_fp16.h>

// Problem constants (B=1 fixed)
#define CC   32
#define DD   24
#define HH   96
#define WW   96
#define HWC  (HH*WW)        // 9216
#define DHW  (DD*HH*WW)     // 221184
#define NG   4
#define CPG  (CC/NG)        // 8
#define OC1  54
#define GN_EPS 1e-5f

// halo-padded activation tensor: [D][98][98][32] f16
#define WP   98
#define PLP  (WP*WP)        // 9604
#define NHP  (DD*PLP*CC)    // padded halves total

#define NBLK_F (DHW/128)    // 1728 fused blocks (128 pts, 2 waves x 64 pts)
#define CHUNK_F (NBLK_F/8)  // 216
#define NBLK_G (DHW/256)    // 864  (gn_apply)
#define CHUNK_G (NBLK_G/8)  // 108

typedef float  f32x4 __attribute__((ext_vector_type(4)));
typedef _Float16 f16x8 __attribute__((ext_vector_type(8)));
typedef unsigned int u32x4 __attribute__((ext_vector_type(4)));

union F16Frag { f16x8 v; __half2 h2[4]; };

// XCD-chunked swizzle: block b -> XCD b%8 gets a contiguous chunk, so every
// kernel's XCD k owns the SAME 27648-point slice (producer/consumer L2 match).
__device__ __forceinline__ int swz(int bid, int chunk) {
    return (bid % 8) * chunk + (bid / 8);
}

// ---- pack weights into per-tap MFMA B-fragments ----
// src: [O][CC][27] fp32. dst: [tap][nt][lane][e] f16, o=nt*16+(lane&15), c=(lane>>4)*8+e.
__global__ void pack_w(const float* __restrict__ src, _Float16* __restrict__ dst,
                       int O, int NT, int n) {
    int idx = blockIdx.x * 256 + threadIdx.x;
    if (idx >= n) return;
    int e    = idx & 7;
    int lane = (idx >> 3) & 63;
    int nt   = (idx >> 9) % NT;
    int tap  = (idx >> 9) / NT;
    int o = nt * 16 + (lane & 15);
    int c = (lane >> 4) * 8 + e;
    float v = (o < O) ? src[(o * CC + c) * 27 + tap] : 0.f;
    dst[idx] = (_Float16)v;
}

// ---- group-norm stats ----
__global__ void gn_stats(const float* __restrict__ x, float* __restrict__ stats) {
    const int g = blockIdx.x >> 5;
    const int s = blockIdx.x & 31;
    const float4* base = (const float4*)(x + (size_t)g * CPG * DHW);
    const int n4 = CPG * DHW / 4;
    float s1 = 0.f, s2 = 0.f;
    for (int idx = s * 256 + threadIdx.x; idx < n4; idx += 32 * 256) {
        float4 v = base[idx];
        s1 += v.x + v.y + v.z + v.w;
        s2 += v.x * v.x + v.y * v.y + v.z * v.z + v.w * v.w;
    }
    for (int off = 32; off > 0; off >>= 1) {
        s1 += __shfl_down(s1, off);
        s2 += __shfl_down(s2, off);
    }
    __shared__ float ls1[4], ls2[4];
    int wid = threadIdx.x >> 6;
    if ((threadIdx.x & 63) == 0) { ls1[wid] = s1; ls2[wid] = s2; }
    __syncthreads();
    if (threadIdx.x == 0) {
        float a = 0.f, b = 0.f;
        for (int i = 0; i < 4; i++) { a += ls1[i]; b += ls2[i]; }
        atomicAdd(&stats[g * 2 + 0], a);
        atomicAdd(&stats[g * 2 + 1], b);
    }
}

// ---- group-norm apply + relu + transpose to halo-padded channels-last f16 ----
__global__ void gn_apply_T(const float* __restrict__ x, const float* __restrict__ stats,
                           const float* __restrict__ gamma, const float* __restrict__ beta,
                           __half* __restrict__ yTp) {
    const int p = swz(blockIdx.x, CHUNK_G) * 256 + threadIdx.x;
    const float invN = 1.0f / (float)(CPG * DHW);
    float mean[NG], rstd[NG];
#pragma unroll
    for (int g = 0; g < NG; g++) {
        mean[g] = stats[2 * g] * invN;
        float var = stats[2 * g + 1] * invN - mean[g] * mean[g];
        rstd[g] = rsqrtf(var + GN_EPS);
    }
    float vals[CC];
#pragma unroll
    for (int c = 0; c < CC; c++) {
        const int g = c >> 3;
        const float ga = gamma[c] * rstd[g];
        const float be = beta[c] - mean[g] * ga;
        vals[c] = fmaxf(0.f, x[(size_t)c * DHW + p] * ga + be);
    }
    union { __half2 h2[16]; u32x4 q[4]; } u;
#pragma unroll
    for (int c = 0; c < 16; c++) u.h2[c] = __floats2half2_rn(vals[2 * c], vals[2 * c + 1]);
    const int d = p / HWC;
    const int rr = p % HWC;
    const int h = rr / WW;
    const int w = rr % WW;
    u32x4* dst = (u32x4*)(yTp + ((size_t)d * PLP + (size_t)(h + 1) * WP + (w + 1)) * CC);
#pragma unroll
    for (int q = 0; q < 4; q++) dst[q] = u.q[q];
}

// ---- FUSED: offset conv (32->54, MFMA) -> LDS -> deformable conv (MFMA) ----
// Per block: 128 points, 2 waves, each wave owns 64 points (m-tiles 0..3).
// Verified C/D mapping: o(col) = nt*16 + (lane&15), point(row) = m*16 + (lane>>4)*4 + reg.
#define OPAD 70   // halves per offset row (64 pts + pad)
__global__ __launch_bounds__(128, 3) void fused_conv(const __half* __restrict__ xTp,
                                                     const _Float16* __restrict__ wBo,
                                                     const float* __restrict__ ob,
                                                     const _Float16* __restrict__ wBd,
                                                     const float* __restrict__ db,
                                                     const float* __restrict__ resid,
                                                     float* __restrict__ outp) {
    __shared__ __align__(16) char lds_raw[CC * 132 * 4];   // 16896 B (>= 2*54*70*2)
    __half* offs_lds = (__half*)lds_raw;
    float*  out_lds  = (float*)lds_raw;

    const int tid  = threadIdx.x;
    const int lane = tid & 63;
    const int wave = tid >> 6;
    const int p0   = swz(blockIdx.x, CHUNK_F) * 128;
    const int pw   = p0 + wave * 64;
    const int d    = pw / HWC;        // 128 | 9216: no d-crossing in a block
    const int rem  = pw % HWC;
    const int mrow = lane & 15;
    const int kg   = lane >> 4;
    const int wbase = wave * (OC1 * OPAD);

    int hq[4], wq[4];
#pragma unroll
    for (int m = 0; m < 4; m++) {
        int rr = rem + m * 16 + mrow;
        hq[m] = rr / WW; wq[m] = rr % WW;
    }

    // ================= Phase A: offset conv (halo-padded, unconditional) ====
    f32x4 aco[4][4];
#pragma unroll
    for (int m = 0; m < 4; m++)
#pragma unroll
        for (int n = 0; n < 4; n++) aco[m][n] = (f32x4){0.f, 0.f, 0.f, 0.f};

    const f16x8* wbo8 = (const f16x8*)wBo;

#pragma unroll 1
    for (int i = 0; i < 3; i++) {
        const int dd = d + i - 1;
        if ((unsigned)dd >= DD) continue;
        const __half* xd = xTp + (size_t)dd * PLP * CC;
#pragma unroll 3
        for (int jk = 0; jk < 9; jk++) {
            const int j = jk / 3, k = jk % 3, tap = i * 9 + jk;
            const f16x8 b0 = wbo8[(tap * 4 + 0) * 64 + lane];
            const f16x8 b1 = wbo8[(tap * 4 + 1) * 64 + lane];
            const f16x8 b2 = wbo8[(tap * 4 + 2) * 64 + lane];
            const f16x8 b3 = wbo8[(tap * 4 + 3) * 64 + lane];
            f16x8 a[4];
#pragma unroll
            for (int m = 0; m < 4; m++)
                a[m] = *(const f16x8*)(xd + (size_t)((hq[m] + j) * WP + wq[m] + k) * CC + kg * 8);
#pragma unroll
            for (int m = 0; m < 4; m++) {
                aco[m][0] = __builtin_amdgcn_mfma_f32_16x16x32_f16(a[m], b0, aco[m][0], 0, 0, 0);
                aco[m][1] = __builtin_amdgcn_mfma_f32_16x16x32_f16(a[m], b1, aco[m][1], 0, 0, 0);
                aco[m][2] = __builtin_amdgcn_mfma_f32_16x16x32_f16(a[m], b2, aco[m][2], 0, 0, 0);
                aco[m][3] = __builtin_amdgcn_mfma_f32_16x16x32_f16(a[m], b3, aco[m][3], 0, 0, 0);
            }
        }
    }

    // ====== Phase B: stage offsets in wave-private LDS (o-major, +bias) =====
    float bo[4];
#pragma unroll
    for (int nt = 0; nt < 4; nt++) {
        const int o = nt * 16 + mrow;
        bo[nt] = (o < OC1) ? ob[o] : 0.f;
    }
#pragma unroll
    for (int m = 0; m < 4; m++) {
#pragma unroll
        for (int nt = 0; nt < 4; nt++) {
            const int o = nt * 16 + mrow;
            if (o < OC1) {
                const int idx = wbase + o * OPAD + m * 16 + kg * 4;
                __half2 lo = __floats2half2_rn(aco[m][nt].x + bo[nt], aco[m][nt].y + bo[nt]);
                __half2 hi = __floats2half2_rn(aco[m][nt].z + bo[nt], aco[m][nt].w + bo[nt]);
                *(__half2*)&offs_lds[idx]     = lo;
                *(__half2*)&offs_lds[idx + 2] = hi;
            }
        }
    }
    // NO barrier: each wave reads only its own offs_lds region (intra-wave
    // LDS ordering via lgkmcnt is sufficient).

    // ================= Phase C: deformable conv =================
    f32x4 acd[4][2];
#pragma unroll
    for (int m = 0; m < 4; m++) {
        acd[m][0] = (f32x4){0.f, 0.f, 0.f, 0.f};
        acd[m][1] = (f32x4){0.f, 0.f, 0.f, 0.f};
    }

    const f16x8* wbd8 = (const f16x8*)wBd;

#pragma unroll 1
    for (int i = 0; i < 3; i++) {
        const int dd = d + i - 1;
        if ((unsigned)dd >= DD) continue;   // zero-padded depth
        const __half* xd = xTp + (size_t)dd * PLP * CC;
#pragma unroll 1
        for (int jk = 0; jk < 9; jk++) {
            const int j = jk / 3, k = jk % 3, tap = i * 9 + jk;
            const f16x8 b0 = wbd8[(tap * 2 + 0) * 64 + lane];
            const f16x8 b1 = wbd8[(tap * 2 + 1) * 64 + lane];
#pragma unroll
            for (int m = 0; m < 4; m++) {
                const int ptl = m * 16 + mrow;
                const float oh = __half2float(offs_lds[wbase + (2 * tap + 0) * OPAD + ptl]);
                const float ov = __half2float(offs_lds[wbase + (2 * tap + 1) * OPAD + ptl]);
                const float hp  = (float)(hq[m] + j - 1) + oh;
                const float wpf = (float)(wq[m] + k - 1) + ov;
                const float h0f = floorf(hp), w0f = floorf(wpf);
                const int h0p = (int)h0f + 1;       // padded coords
                const int w0p = (int)w0f + 1;
                const float lh = hp - h0f, lw = wpf - w0f;
                F16Frag a00, a01, a10, a11, A;
                float c00, c01, c10, c11;
                // fast path: sample window within padded tensor; zero halo
                // implements boundary masking exactly (h0 in [-1,H-1], w0 in [-1,W-1])
                if (__all((unsigned)h0p <= (unsigned)HH && (unsigned)w0p <= (unsigned)WW)) {
                    const __half* g = xd + (size_t)(h0p * WP + w0p) * CC + kg * 8;
                    a00.v = *(const f16x8*)g;
                    a01.v = *(const f16x8*)(g + CC);
                    a10.v = *(const f16x8*)(g + WP * CC);
                    a11.v = *(const f16x8*)(g + WP * CC + CC);
                    c00 = (1.f - lh) * (1.f - lw);
                    c01 = (1.f - lh) * lw;
                    c10 = lh * (1.f - lw);
                    c11 = lh * lw;
                } else {
                    const int h0 = h0p - 1, w0 = w0p - 1;
                    const bool hv0 = (h0 >= 0) && (h0 < HH);
                    const bool hv1 = (h0 >= -1) && (h0 < HH - 1);
                    const bool wv0 = (w0 >= 0) && (w0 < WW);
                    const bool wv1 = (w0 >= -1) && (w0 < WW - 1);
                    c00 = (hv0 && wv0) ? (1.f - lh) * (1.f - lw) : 0.f;
                    c01 = (hv0 && wv1) ? (1.f - lh) * lw : 0.f;
                    c10 = (hv1 && wv0) ? lh * (1.f - lw) : 0.f;
                    c11 = (hv1 && wv1) ? lh * lw : 0.f;
                    const int h0c = min(max(h0, 0), HH - 1) + 1;
                    const int h1c = min(max(h0 + 1, 0), HH - 1) + 1;
                    const int w0c = min(max(w0, 0), WW - 1) + 1;
                    const int w1c = min(max(w0 + 1, 0), WW - 1) + 1;
                    a00.v = *(const f16x8*)(xd + (size_t)(h0c * WP + w0c) * CC + kg * 8);
                    a01.v = *(const f16x8*)(xd + (size_t)(h0c * WP + w1c) * CC + kg * 8);
                    a10.v = *(const f16x8*)(xd + (size_t)(h1c * WP + w0c) * CC + kg * 8);
                    a11.v = *(const f16x8*)(xd + (size_t)(h1c * WP + w1c) * CC + kg * 8);
                }
                const __half2 C00 = __float2half2_rn(c00);
                const __half2 C01 = __float2half2_rn(c01);
                const __half2 C10 = __float2half2_rn(c10);
                const __half2 C11 = __float2half2_rn(c11);
#pragma unroll
                for (int r = 0; r < 4; r++) {
                    __half2 t = __hmul2(C00, a00.h2[r]);
                    t = __hfma2(C01, a01.h2[r], t);
                    t = __hfma2(C10, a10.h2[r], t);
                    t = __hfma2(C11, a11.h2[r], t);
                    A.h2[r] = t;
                }
                acd[m][0] = __builtin_amdgcn_mfma_f32_16x16x32_f16(A.v, b0, acd[m][0], 0, 0, 0);
                acd[m][1] = __builtin_amdgcn_mfma_f32_16x16x32_f16(A.v, b1, acd[m][1], 0, 0, 0);
            }
        }
    }
    __syncthreads();   // offsets dead; reuse LDS for output staging

    // ================= Phase D: stage + coalesced copy-out =================
#pragma unroll
    for (int m = 0; m < 4; m++)
#pragma unroll
        for (int nt = 0; nt < 2; nt++) {
            const int o = nt * 16 + mrow;
            *(f32x4*)&out_lds[o * 132 + wave * 64 + m * 16 + kg * 4] = acd[m][nt];
        }
    __syncthreads();
    if (resid) {
#pragma unroll 1
        for (int o = 0; o < CC; o++) {
            float v = out_lds[o * 132 + tid] + db[o] + resid[(size_t)o * DHW + p0 + tid];
            outp[(size_t)o * DHW + p0 + tid] = v;
        }
    } else {
#pragma unroll 1
        for (int o = 0; o < CC; o++)
            outp[(size_t)o * DHW + p0 + tid] = out_lds[o * 132 + tid] + db[o];
    }
}

extern "C" void kernel_launch(void* const* d_in, const int* in_sizes, int n_in,
                              void* d_out, int out_size, void* d_ws, size_t ws_size,
                              hipStream_t stream) {
    const float* x   = (const float*)d_in[0];
    const float* g1  = (const float*)d_in[1];
    const float* be1 = (const float*)d_in[2];
    const float* g2  = (const float*)d_in[3];
    const float* be2 = (const float*)d_in[4];
    const float* ow1 = (const float*)d_in[5];
    const float* ob1 = (const float*)d_in[6];
    const float* dw1 = (const float*)d_in[7];
    const float* db1 = (const float*)d_in[8];
    const float* ow2 = (const float*)d_in[9];
    const float* ob2 = (const float*)d_in[10];
    const float* dw2 = (const float*)d_in[11];
    const float* db2 = (const float*)d_in[12];
    float* out = (float*)d_out;
    float* ws  = (float*)d_ws;

    // ws layout (float offsets)
    float*    stats = ws;                           // 16
    _Float16* wBo1  = (_Float16*)(ws + 256);        // 55296 h = 27648 f
    _Float16* wBd1  = (_Float16*)(ws + 27904);      // 27648 h = 13824 f
    _Float16* wBo2  = (_Float16*)(ws + 41728);      // 27648 f
    _Float16* wBd2  = (_Float16*)(ws + 69376);      // 13824 f
    __half*   hTp   = (__half*)(ws + 83200);        // padded: 24*9604*32 h = 3,687,936 f

    (void)hipMemsetAsync(stats, 0, 16 * sizeof(float), stream);
    (void)hipMemsetAsync(hTp, 0, (size_t)NHP * sizeof(__half), stream);  // zero halo
    pack_w<<<(27 * 4 * 512 + 255) / 256, 256, 0, stream>>>(ow1, wBo1, 54, 4, 27 * 4 * 512);
    pack_w<<<(27 * 2 * 512 + 255) / 256, 256, 0, stream>>>(dw1, wBd1, 32, 2, 27 * 2 * 512);
    pack_w<<<(27 * 4 * 512 + 255) / 256, 256, 0, stream>>>(ow2, wBo2, 54, 4, 27 * 4 * 512);
    pack_w<<<(27 * 2 * 512 + 255) / 256, 256, 0, stream>>>(dw2, wBd2, 32, 2, 27 * 2 * 512);

    // block 1
    gn_stats<<<NG * 32, 256, 0, stream>>>(x, stats + 0);
    gn_apply_T<<<NBLK_G, 256, 0, stream>>>(x, stats + 0, g1, be1, hTp);
    fused_conv<<<NBLK_F, 128, 0, stream>>>(hTp, wBo1, ob1, wBd1, db1, nullptr, out);

    // block 2 (input = block-1 output in d_out; halo stays zero)
    gn_stats<<<NG * 32, 256, 0, stream>>>(out, stats + 8);
    gn_apply_T<<<NBLK_G, 256, 0, stream>>>(out, stats + 8, g2, be2, hTp);
    fused_conv<<<NBLK_F, 128, 0, stream>>>(hTp, wBo2, ob2, wBd2, db2, x, out);
}

// Round 11
// 427.980 us; speedup vs baseline: 1.0532x; 1.0058x over previous
//
#include <hip/hip_runtime.h>
#include <hip/hip_fp16.h>

// Problem constants (B=1 fixed)
#define CC   32
#define DD   24
#define HH   96
#define WW   96
#define HWC  (HH*WW)        // 9216
#define DHW  (DD*HH*WW)     // 221184
#define NG   4
#define CPG  (CC/NG)        // 8
#define OC1  54
#define GN_EPS 1e-5f

// halo-padded activation tensor: [D][98][98][32] f16
#define WP   98
#define PLP  (WP*WP)        // 9604
#define NHP  (DD*PLP*CC)    // padded halves total

#define NBLK_F (DHW/128)    // 1728 fused blocks (128 pts, 2 waves x 64 pts)
#define CHUNK_F (NBLK_F/8)  // 216
#define NBLK_G (DHW/256)    // 864  (gn_apply)
#define CHUNK_G (NBLK_G/8)  // 108

typedef float  f32x4 __attribute__((ext_vector_type(4)));
typedef _Float16 f16x8 __attribute__((ext_vector_type(8)));
typedef unsigned int u32x4 __attribute__((ext_vector_type(4)));

union F16Frag { f16x8 v; __half2 h2[4]; };

// XCD-chunked swizzle: block b -> XCD b%8 gets a contiguous chunk, so every
// kernel's XCD k owns the SAME 27648-point slice (producer/consumer L2 match).
__device__ __forceinline__ int swz(int bid, int chunk) {
    return (bid % 8) * chunk + (bid / 8);
}

// ---- pack weights into per-tap MFMA B-fragments ----
// src: [O][CC][27] fp32. dst: [tap][nt][lane][e] f16, o=nt*16+(lane&15), c=(lane>>4)*8+e.
__global__ void pack_w(const float* __restrict__ src, _Float16* __restrict__ dst,
                       int O, int NT, int n) {
    int idx = blockIdx.x * 256 + threadIdx.x;
    if (idx >= n) return;
    int e    = idx & 7;
    int lane = (idx >> 3) & 63;
    int nt   = (idx >> 9) % NT;
    int tap  = (idx >> 9) / NT;
    int o = nt * 16 + (lane & 15);
    int c = (lane >> 4) * 8 + e;
    float v = (o < O) ? src[(o * CC + c) * 27 + tap] : 0.f;
    dst[idx] = (_Float16)v;
}

// ---- group-norm stats ----
__global__ void gn_stats(const float* __restrict__ x, float* __restrict__ stats) {
    const int g = blockIdx.x >> 5;
    const int s = blockIdx.x & 31;
    const float4* base = (const float4*)(x + (size_t)g * CPG * DHW);
    const int n4 = CPG * DHW / 4;
    float s1 = 0.f, s2 = 0.f;
    for (int idx = s * 256 + threadIdx.x; idx < n4; idx += 32 * 256) {
        float4 v = base[idx];
        s1 += v.x + v.y + v.z + v.w;
        s2 += v.x * v.x + v.y * v.y + v.z * v.z + v.w * v.w;
    }
    for (int off = 32; off > 0; off >>= 1) {
        s1 += __shfl_down(s1, off);
        s2 += __shfl_down(s2, off);
    }
    __shared__ float ls1[4], ls2[4];
    int wid = threadIdx.x >> 6;
    if ((threadIdx.x & 63) == 0) { ls1[wid] = s1; ls2[wid] = s2; }
    __syncthreads();
    if (threadIdx.x == 0) {
        float a = 0.f, b = 0.f;
        for (int i = 0; i < 4; i++) { a += ls1[i]; b += ls2[i]; }
        atomicAdd(&stats[g * 2 + 0], a);
        atomicAdd(&stats[g * 2 + 1], b);
    }
}

// ---- group-norm apply + relu + transpose to halo-padded channels-last f16 ----
__global__ void gn_apply_T(const float* __restrict__ x, const float* __restrict__ stats,
                           const float* __restrict__ gamma, const float* __restrict__ beta,
                           __half* __restrict__ yTp) {
    const int p = swz(blockIdx.x, CHUNK_G) * 256 + threadIdx.x;
    const float invN = 1.0f / (float)(CPG * DHW);
    float mean[NG], rstd[NG];
#pragma unroll
    for (int g = 0; g < NG; g++) {
        mean[g] = stats[2 * g] * invN;
        float var = stats[2 * g + 1] * invN - mean[g] * mean[g];
        rstd[g] = rsqrtf(var + GN_EPS);
    }
    float vals[CC];
#pragma unroll
    for (int c = 0; c < CC; c++) {
        const int g = c >> 3;
        const float ga = gamma[c] * rstd[g];
        const float be = beta[c] - mean[g] * ga;
        vals[c] = fmaxf(0.f, x[(size_t)c * DHW + p] * ga + be);
    }
    union { __half2 h2[16]; u32x4 q[4]; } u;
#pragma unroll
    for (int c = 0; c < 16; c++) u.h2[c] = __floats2half2_rn(vals[2 * c], vals[2 * c + 1]);
    const int d = p / HWC;
    const int rr = p % HWC;
    const int h = rr / WW;
    const int w = rr % WW;
    u32x4* dst = (u32x4*)(yTp + ((size_t)d * PLP + (size_t)(h + 1) * WP + (w + 1)) * CC);
#pragma unroll
    for (int q = 0; q < 4; q++) dst[q] = u.q[q];
}

// ---- FUSED: offset conv (32->54, MFMA) -> LDS -> deformable conv (MFMA) ----
// Per block: 128 points, 2 waves, each wave owns 64 points (m-tiles 0..3).
// Verified C/D mapping: o(col) = nt*16 + (lane&15), point(row) = m*16 + (lane>>4)*4 + reg.
#define OPAD 70   // halves per offset row (64 pts + pad)
__global__ __launch_bounds__(128, 3) void fused_conv(const __half* __restrict__ xTp,
                                                     const _Float16* __restrict__ wBo,
                                                     const float* __restrict__ ob,
                                                     const _Float16* __restrict__ wBd,
                                                     const float* __restrict__ db,
                                                     const float* __restrict__ resid,
                                                     float* __restrict__ outp) {
    __shared__ __align__(16) char lds_raw[CC * 132 * 4];   // 16896 B (>= 2*54*70*2)
    __half* offs_lds = (__half*)lds_raw;
    float*  out_lds  = (float*)lds_raw;

    const int tid  = threadIdx.x;
    const int lane = tid & 63;
    const int wave = tid >> 6;
    const int p0   = swz(blockIdx.x, CHUNK_F) * 128;
    const int pw   = p0 + wave * 64;
    const int d    = pw / HWC;        // 128 | 9216: no d-crossing in a block
    const int rem  = pw % HWC;
    const int mrow = lane & 15;
    const int kg   = lane >> 4;
    const int wbase = wave * (OC1 * OPAD);

    int hq[4], wq[4];
#pragma unroll
    for (int m = 0; m < 4; m++) {
        int rr = rem + m * 16 + mrow;
        hq[m] = rr / WW; wq[m] = rr % WW;
    }

    // ================= Phase A: offset conv (halo-padded, unconditional) ====
    f32x4 aco[4][4];
#pragma unroll
    for (int m = 0; m < 4; m++)
#pragma unroll
        for (int n = 0; n < 4; n++) aco[m][n] = (f32x4){0.f, 0.f, 0.f, 0.f};

    const f16x8* wbo8 = (const f16x8*)wBo;

#pragma unroll 1
    for (int i = 0; i < 3; i++) {
        const int dd = d + i - 1;
        if ((unsigned)dd >= DD) continue;
        const __half* xd = xTp + (size_t)dd * PLP * CC;
#pragma unroll 3
        for (int jk = 0; jk < 9; jk++) {
            const int j = jk / 3, k = jk % 3, tap = i * 9 + jk;
            const f16x8 b0 = wbo8[(tap * 4 + 0) * 64 + lane];
            const f16x8 b1 = wbo8[(tap * 4 + 1) * 64 + lane];
            const f16x8 b2 = wbo8[(tap * 4 + 2) * 64 + lane];
            const f16x8 b3 = wbo8[(tap * 4 + 3) * 64 + lane];
            f16x8 a[4];
#pragma unroll
            for (int m = 0; m < 4; m++)
                a[m] = *(const f16x8*)(xd + (size_t)((hq[m] + j) * WP + wq[m] + k) * CC + kg * 8);
#pragma unroll
            for (int m = 0; m < 4; m++) {
                aco[m][0] = __builtin_amdgcn_mfma_f32_16x16x32_f16(a[m], b0, aco[m][0], 0, 0, 0);
                aco[m][1] = __builtin_amdgcn_mfma_f32_16x16x32_f16(a[m], b1, aco[m][1], 0, 0, 0);
                aco[m][2] = __builtin_amdgcn_mfma_f32_16x16x32_f16(a[m], b2, aco[m][2], 0, 0, 0);
                aco[m][3] = __builtin_amdgcn_mfma_f32_16x16x32_f16(a[m], b3, aco[m][3], 0, 0, 0);
            }
        }
    }

    // ====== Phase B: stage offsets in wave-private LDS (o-major, +bias) =====
    float bo[4];
#pragma unroll
    for (int nt = 0; nt < 4; nt++) {
        const int o = nt * 16 + mrow;
        bo[nt] = (o < OC1) ? ob[o] : 0.f;
    }
#pragma unroll
    for (int m = 0; m < 4; m++) {
#pragma unroll
        for (int nt = 0; nt < 4; nt++) {
            const int o = nt * 16 + mrow;
            if (o < OC1) {
                const int idx = wbase + o * OPAD + m * 16 + kg * 4;
                __half2 lo = __floats2half2_rn(aco[m][nt].x + bo[nt], aco[m][nt].y + bo[nt]);
                __half2 hi = __floats2half2_rn(aco[m][nt].z + bo[nt], aco[m][nt].w + bo[nt]);
                *(__half2*)&offs_lds[idx]     = lo;
                *(__half2*)&offs_lds[idx + 2] = hi;
            }
        }
    }
    // NO barrier: each wave reads only its own offs_lds region (intra-wave
    // LDS ordering via lgkmcnt is sufficient).

    // ================= Phase C: deformable conv (branchless halo math) ======
    f32x4 acd[4][2];
#pragma unroll
    for (int m = 0; m < 4; m++) {
        acd[m][0] = (f32x4){0.f, 0.f, 0.f, 0.f};
        acd[m][1] = (f32x4){0.f, 0.f, 0.f, 0.f};
    }

    const f16x8* wbd8 = (const f16x8*)wBd;

#pragma unroll 1
    for (int i = 0; i < 3; i++) {
        const int dd = d + i - 1;
        if ((unsigned)dd >= DD) continue;   // zero-padded depth
        const __half* xd = xTp + (size_t)dd * PLP * CC;
#pragma unroll 3
        for (int jk = 0; jk < 9; jk++) {
            const int j = jk / 3, k = jk % 3, tap = i * 9 + jk;
            const f16x8 b0 = wbd8[(tap * 2 + 0) * 64 + lane];
            const f16x8 b1 = wbd8[(tap * 2 + 1) * 64 + lane];
            // batch 1: addresses + coeffs for all 4 m (branchless).
            // Zero halo makes masking exact for h0p,w0p in [0,96]; anything
            // outside that window is a fully-zero sample (all 4 corners
            // invalid in the reference), handled by zeroing the coeffs.
            int ib[4];
            float c00[4], c01[4], c10[4], c11[4];
#pragma unroll
            for (int m = 0; m < 4; m++) {
                const int ptl = m * 16 + mrow;
                const float oh = __half2float(offs_lds[wbase + (2 * tap + 0) * OPAD + ptl]);
                const float ov = __half2float(offs_lds[wbase + (2 * tap + 1) * OPAD + ptl]);
                const float hp  = (float)(hq[m] + j - 1) + oh;
                const float wpf = (float)(wq[m] + k - 1) + ov;
                const float h0f = floorf(hp), w0f = floorf(wpf);
                const float lh = hp - h0f, lw = wpf - w0f;
                const int h0p = (int)h0f + 1;   // padded coords
                const int w0p = (int)w0f + 1;
                const bool inb = ((unsigned)h0p <= 96u) && ((unsigned)w0p <= 96u);
                const int hc = min(max(h0p, 0), 96);
                const int wc = min(max(w0p, 0), 96);
                ib[m] = hc * WP + wc;
                const float omh = 1.f - lh, omw = 1.f - lw;
                c00[m] = inb ? omh * omw : 0.f;
                c01[m] = inb ? omh * lw  : 0.f;
                c10[m] = inb ? lh * omw  : 0.f;
                c11[m] = inb ? lh * lw   : 0.f;
            }
            // batch 2: gathers (1 base + 3 fixed offsets) + blend + MFMA
#pragma unroll
            for (int m = 0; m < 4; m++) {
                const __half* g = xd + (size_t)ib[m] * CC + kg * 8;
                F16Frag a00, a01, a10, a11, A;
                a00.v = *(const f16x8*)g;
                a01.v = *(const f16x8*)(g + CC);
                a10.v = *(const f16x8*)(g + WP * CC);
                a11.v = *(const f16x8*)(g + WP * CC + CC);
                const __half2 C00 = __float2half2_rn(c00[m]);
                const __half2 C01 = __float2half2_rn(c01[m]);
                const __half2 C10 = __float2half2_rn(c10[m]);
                const __half2 C11 = __float2half2_rn(c11[m]);
#pragma unroll
                for (int r = 0; r < 4; r++) {
                    __half2 t = __hmul2(C00, a00.h2[r]);
                    t = __hfma2(C01, a01.h2[r], t);
                    t = __hfma2(C10, a10.h2[r], t);
                    t = __hfma2(C11, a11.h2[r], t);
                    A.h2[r] = t;
                }
                acd[m][0] = __builtin_amdgcn_mfma_f32_16x16x32_f16(A.v, b0, acd[m][0], 0, 0, 0);
                acd[m][1] = __builtin_amdgcn_mfma_f32_16x16x32_f16(A.v, b1, acd[m][1], 0, 0, 0);
            }
        }
    }
    __syncthreads();   // offsets dead; reuse LDS for output staging

    // ================= Phase D: stage + coalesced copy-out =================
#pragma unroll
    for (int m = 0; m < 4; m++)
#pragma unroll
        for (int nt = 0; nt < 2; nt++) {
            const int o = nt * 16 + mrow;
            *(f32x4*)&out_lds[o * 132 + wave * 64 + m * 16 + kg * 4] = acd[m][nt];
        }
    __syncthreads();
    if (resid) {
#pragma unroll 1
        for (int o = 0; o < CC; o++) {
            float v = out_lds[o * 132 + tid] + db[o] + resid[(size_t)o * DHW + p0 + tid];
            outp[(size_t)o * DHW + p0 + tid] = v;
        }
    } else {
#pragma unroll 1
        for (int o = 0; o < CC; o++)
            outp[(size_t)o * DHW + p0 + tid] = out_lds[o * 132 + tid] + db[o];
    }
}

extern "C" void kernel_launch(void* const* d_in, const int* in_sizes, int n_in,
                              void* d_out, int out_size, void* d_ws, size_t ws_size,
                              hipStream_t stream) {
    const float* x   = (const float*)d_in[0];
    const float* g1  = (const float*)d_in[1];
    const float* be1 = (const float*)d_in[2];
    const float* g2  = (const float*)d_in[3];
    const float* be2 = (const float*)d_in[4];
    const float* ow1 = (const float*)d_in[5];
    const float* ob1 = (const float*)d_in[6];
    const float* dw1 = (const float*)d_in[7];
    const float* db1 = (const float*)d_in[8];
    const float* ow2 = (const float*)d_in[9];
    const float* ob2 = (const float*)d_in[10];
    const float* dw2 = (const float*)d_in[11];
    const float* db2 = (const float*)d_in[12];
    float* out = (float*)d_out;
    float* ws  = (float*)d_ws;

    // ws layout (float offsets)
    float*    stats = ws;                           // 16
    _Float16* wBo1  = (_Float16*)(ws + 256);        // 55296 h = 27648 f
    _Float16* wBd1  = (_Float16*)(ws + 27904);      // 27648 h = 13824 f
    _Float16* wBo2  = (_Float16*)(ws + 41728);      // 27648 f
    _Float16* wBd2  = (_Float16*)(ws + 69376);      // 13824 f
    __half*   hTp   = (__half*)(ws + 83200);        // padded: 24*9604*32 h = 3,687,936 f

    (void)hipMemsetAsync(stats, 0, 16 * sizeof(float), stream);
    (void)hipMemsetAsync(hTp, 0, (size_t)NHP * sizeof(__half), stream);  // zero halo
    pack_w<<<(27 * 4 * 512 + 255) / 256, 256, 0, stream>>>(ow1, wBo1, 54, 4, 27 * 4 * 512);
    pack_w<<<(27 * 2 * 512 + 255) / 256, 256, 0, stream>>>(dw1, wBd1, 32, 2, 27 * 2 * 512);
    pack_w<<<(27 * 4 * 512 + 255) / 256, 256, 0, stream>>>(ow2, wBo2, 54, 4, 27 * 4 * 512);
    pack_w<<<(27 * 2 * 512 + 255) / 256, 256, 0, stream>>>(dw2, wBd2, 32, 2, 27 * 2 * 512);

    // block 1
    gn_stats<<<NG * 32, 256, 0, stream>>>(x, stats + 0);
    gn_apply_T<<<NBLK_G, 256, 0, stream>>>(x, stats + 0, g1, be1, hTp);
    fused_conv<<<NBLK_F, 128, 0, stream>>>(hTp, wBo1, ob1, wBd1, db1, nullptr, out);

    // block 2 (input = block-1 output in d_out; halo stays zero)
    gn_stats<<<NG * 32, 256, 0, stream>>>(out, stats + 8);
    gn_apply_T<<<NBLK_G, 256, 0, stream>>>(out, stats + 8, g2, be2, hTp);
    fused_conv<<<NBLK_F, 128, 0, stream>>>(hTp, wBo2, ob2, wBd2, db2, x, out);
}

// Round 12
// 368.235 us; speedup vs baseline: 1.2241x; 1.1622x over previous
//
#include <hip/hip_runtime.h>
#include <hip/hip_fp16.h>

// Problem constants (B=1 fixed)
#define CC   32
#define DD   24
#define HH   96
#define WW   96
#define HWC  (HH*WW)        // 9216
#define DHW  (DD*HH*WW)     // 221184
#define NG   4
#define CPG  (CC/NG)        // 8
#define OC1  54
#define GN_EPS 1e-5f

#define NBLK_F (DHW/128)    // 1728 fused blocks (128 pts, 2 waves x 64 pts)
#define CHUNK_F (NBLK_F/8)  // 216
#define NBLK_G (DHW/256)    // 864  (gn_apply)
#define CHUNK_G (NBLK_G/8)  // 108

typedef float  f32x4 __attribute__((ext_vector_type(4)));
typedef _Float16 f16x8 __attribute__((ext_vector_type(8)));
typedef unsigned int u32x4 __attribute__((ext_vector_type(4)));

union F16Frag { f16x8 v; __half2 h2[4]; };

// XCD-chunked swizzle: block b -> XCD b%8 gets a contiguous chunk, so every
// kernel's XCD k owns the SAME 27648-point slice (producer/consumer L2 match).
__device__ __forceinline__ int swz(int bid, int chunk) {
    return (bid % 8) * chunk + (bid / 8);
}

// ---- pack weights into per-tap MFMA B-fragments ----
// src: [O][CC][27] fp32. dst: [tap][nt][lane][e] f16, o=nt*16+(lane&15), c=(lane>>4)*8+e.
__global__ void pack_w(const float* __restrict__ src, _Float16* __restrict__ dst,
                       int O, int NT, int n) {
    int idx = blockIdx.x * 256 + threadIdx.x;
    if (idx >= n) return;
    int e    = idx & 7;
    int lane = (idx >> 3) & 63;
    int nt   = (idx >> 9) % NT;
    int tap  = (idx >> 9) / NT;
    int o = nt * 16 + (lane & 15);
    int c = (lane >> 4) * 8 + e;
    float v = (o < O) ? src[(o * CC + c) * 27 + tap] : 0.f;
    dst[idx] = (_Float16)v;
}

// ---- group-norm stats ----
__global__ void gn_stats(const float* __restrict__ x, float* __restrict__ stats) {
    const int g = blockIdx.x >> 5;
    const int s = blockIdx.x & 31;
    const float4* base = (const float4*)(x + (size_t)g * CPG * DHW);
    const int n4 = CPG * DHW / 4;
    float s1 = 0.f, s2 = 0.f;
    for (int idx = s * 256 + threadIdx.x; idx < n4; idx += 32 * 256) {
        float4 v = base[idx];
        s1 += v.x + v.y + v.z + v.w;
        s2 += v.x * v.x + v.y * v.y + v.z * v.z + v.w * v.w;
    }
    for (int off = 32; off > 0; off >>= 1) {
        s1 += __shfl_down(s1, off);
        s2 += __shfl_down(s2, off);
    }
    __shared__ float ls1[4], ls2[4];
    int wid = threadIdx.x >> 6;
    if ((threadIdx.x & 63) == 0) { ls1[wid] = s1; ls2[wid] = s2; }
    __syncthreads();
    if (threadIdx.x == 0) {
        float a = 0.f, b = 0.f;
        for (int i = 0; i < 4; i++) { a += ls1[i]; b += ls2[i]; }
        atomicAdd(&stats[g * 2 + 0], a);
        atomicAdd(&stats[g * 2 + 1], b);
    }
}

// ---- group-norm apply + relu + transpose to channels-last f16 ----
__global__ void gn_apply_T(const float* __restrict__ x, const float* __restrict__ stats,
                           const float* __restrict__ gamma, const float* __restrict__ beta,
                           __half* __restrict__ yT) {
    const int p = swz(blockIdx.x, CHUNK_G) * 256 + threadIdx.x;
    const float invN = 1.0f / (float)(CPG * DHW);
    float mean[NG], rstd[NG];
#pragma unroll
    for (int g = 0; g < NG; g++) {
        mean[g] = stats[2 * g] * invN;
        float var = stats[2 * g + 1] * invN - mean[g] * mean[g];
        rstd[g] = rsqrtf(var + GN_EPS);
    }
    float vals[CC];
#pragma unroll
    for (int c = 0; c < CC; c++) {
        const int g = c >> 3;
        const float ga = gamma[c] * rstd[g];
        const float be = beta[c] - mean[g] * ga;
        vals[c] = fmaxf(0.f, x[(size_t)c * DHW + p] * ga + be);
    }
    union { __half2 h2[16]; u32x4 q[4]; } u;
#pragma unroll
    for (int c = 0; c < 16; c++) u.h2[c] = __floats2half2_rn(vals[2 * c], vals[2 * c + 1]);
    u32x4* dst = (u32x4*)(yT + (size_t)p * CC);
#pragma unroll
    for (int q = 0; q < 4; q++) dst[q] = u.q[q];
}

// ---- FUSED: offset conv (32->54, MFMA) -> LDS -> deformable conv (MFMA) ----
// Per block: 128 points, 2 waves, each wave owns 64 points (m-tiles 0..3).
// Verified C/D mapping: o(col) = nt*16 + (lane&15), point(row) = m*16 + (lane>>4)*4 + reg.
// Offset LDS layout (NEW): wave-private [tap][pt][{oh,ov}] halves -> one u32
// read per (tap,point); reads software-pipelined one tap ahead in phase C.
__global__ __launch_bounds__(128, 3) void fused_conv(const __half* __restrict__ xT,
                                                     const _Float16* __restrict__ wBo,
                                                     const float* __restrict__ ob,
                                                     const _Float16* __restrict__ wBd,
                                                     const float* __restrict__ db,
                                                     const float* __restrict__ resid,
                                                     float* __restrict__ outp) {
    __shared__ __align__(16) char lds_raw[CC * 132 * 4];   // 16896 B (>= 2*27*64*2*2 = 13824)
    __half* offs_lds = (__half*)lds_raw;
    float*  out_lds  = (float*)lds_raw;

    const int tid  = threadIdx.x;
    const int lane = tid & 63;
    const int wave = tid >> 6;
    const int p0   = swz(blockIdx.x, CHUNK_F) * 128;
    const int pw   = p0 + wave * 64;
    const int d    = pw / HWC;        // 128 | 9216: no d-crossing in a block
    const int rem  = pw % HWC;
    const int mrow = lane & 15;
    const int kg   = lane >> 4;
    const int wbase2 = wave * (27 * 64 * 2);   // halves

    int hq[4], wq[4];
#pragma unroll
    for (int m = 0; m < 4; m++) {
        int rr = rem + m * 16 + mrow;
        hq[m] = rr / WW; wq[m] = rr % WW;
    }

    // ================= Phase A: offset conv, acc_o[m][nt] =================
    f32x4 aco[4][4];
#pragma unroll
    for (int m = 0; m < 4; m++)
#pragma unroll
        for (int n = 0; n < 4; n++) aco[m][n] = (f32x4){0.f, 0.f, 0.f, 0.f};

    const f16x8* wbo8 = (const f16x8*)wBo;

#pragma unroll 1
    for (int i = 0; i < 3; i++) {
        const int dd = d + i - 1;
        if ((unsigned)dd >= DD) continue;
        const __half* xd = xT + (size_t)dd * HWC * CC;
#pragma unroll 3
        for (int jk = 0; jk < 9; jk++) {
            const int j = jk / 3, k = jk % 3, tap = i * 9 + jk;
            const f16x8 b0 = wbo8[(tap * 4 + 0) * 64 + lane];
            const f16x8 b1 = wbo8[(tap * 4 + 1) * 64 + lane];
            const f16x8 b2 = wbo8[(tap * 4 + 2) * 64 + lane];
            const f16x8 b3 = wbo8[(tap * 4 + 3) * 64 + lane];
            f16x8 a[4];
#pragma unroll
            for (int m = 0; m < 4; m++) {
                const int hh = hq[m] + j - 1;
                const int ww = wq[m] + k - 1;
                a[m] = (f16x8){0, 0, 0, 0, 0, 0, 0, 0};
                if ((unsigned)hh < HH && (unsigned)ww < WW)
                    a[m] = *(const f16x8*)(xd + (size_t)(hh * WW + ww) * CC + kg * 8);
            }
#pragma unroll
            for (int m = 0; m < 4; m++) {
                aco[m][0] = __builtin_amdgcn_mfma_f32_16x16x32_f16(a[m], b0, aco[m][0], 0, 0, 0);
                aco[m][1] = __builtin_amdgcn_mfma_f32_16x16x32_f16(a[m], b1, aco[m][1], 0, 0, 0);
                aco[m][2] = __builtin_amdgcn_mfma_f32_16x16x32_f16(a[m], b2, aco[m][2], 0, 0, 0);
                aco[m][3] = __builtin_amdgcn_mfma_f32_16x16x32_f16(a[m], b3, aco[m][3], 0, 0, 0);
            }
        }
    }

    // ====== Phase B: stage offsets interleaved [tap][pt][{oh,ov}] (+bias) ====
    float bo[4];
#pragma unroll
    for (int nt = 0; nt < 4; nt++) {
        const int o = nt * 16 + mrow;
        bo[nt] = (o < OC1) ? ob[o] : 0.f;
    }
#pragma unroll
    for (int m = 0; m < 4; m++) {
#pragma unroll
        for (int nt = 0; nt < 4; nt++) {
            const int o = nt * 16 + mrow;
            if (o < OC1) {
                const int tap = o >> 1, par = o & 1;
#pragma unroll
                for (int r = 0; r < 4; r++) {
                    const int pt = m * 16 + kg * 4 + r;
                    offs_lds[wbase2 + tap * 128 + pt * 2 + par] =
                        __float2half(aco[m][nt][r] + bo[nt]);
                }
            }
        }
    }
    __syncthreads();

    // ================= Phase C: deformable conv =================
    f32x4 acd[4][2];
#pragma unroll
    for (int m = 0; m < 4; m++) {
        acd[m][0] = (f32x4){0.f, 0.f, 0.f, 0.f};
        acd[m][1] = (f32x4){0.f, 0.f, 0.f, 0.f};
    }

    const f16x8* wbd8 = (const f16x8*)wBd;

#pragma unroll 1
    for (int i = 0; i < 3; i++) {
        const int dd = d + i - 1;
        if ((unsigned)dd >= DD) continue;   // zero-padded depth
        const __half* xd = xT + (size_t)dd * HWC * CC;
        // preload offsets for first tap of this slice (one u32 per m)
        unsigned int offn[4];
#pragma unroll
        for (int m = 0; m < 4; m++)
            offn[m] = *(const unsigned int*)&offs_lds[wbase2 + (i * 9) * 128 + (m * 16 + mrow) * 2];
#pragma unroll 1
        for (int jk = 0; jk < 9; jk++) {
            const int j = jk / 3, k = jk % 3, tap = i * 9 + jk;
            const f16x8 b0 = wbd8[(tap * 2 + 0) * 64 + lane];
            const f16x8 b1 = wbd8[(tap * 2 + 1) * 64 + lane];
            unsigned int offc[4];
#pragma unroll
            for (int m = 0; m < 4; m++) offc[m] = offn[m];
            if (jk < 8) {   // issue next tap's offset reads early (pipeline)
#pragma unroll
                for (int m = 0; m < 4; m++)
                    offn[m] = *(const unsigned int*)&offs_lds[wbase2 + (tap + 1) * 128 + (m * 16 + mrow) * 2];
            }
            // batch 1: offsets (regs) -> addresses + coeffs for all 4 m
            int i00[4], i01[4], i10[4], i11[4];
            float c00[4], c01[4], c10[4], c11[4];
#pragma unroll
            for (int m = 0; m < 4; m++) {
                const __half2 o2 = *(__half2*)&offc[m];
                const float oh = __half2float(__low2half(o2));
                const float ov = __half2float(__high2half(o2));
                const float hp  = (float)(hq[m] + j - 1) + oh;
                const float wpf = (float)(wq[m] + k - 1) + ov;
                const float h0f = floorf(hp), w0f = floorf(wpf);
                const int h0 = (int)h0f, w0 = (int)w0f;
                const float lh = hp - h0f, lw = wpf - w0f;
                const bool hv0 = (h0 >= 0) && (h0 < HH);
                const bool hv1 = (h0 >= -1) && (h0 < HH - 1);
                const bool wv0 = (w0 >= 0) && (w0 < WW);
                const bool wv1 = (w0 >= -1) && (w0 < WW - 1);
                c00[m] = (hv0 && wv0) ? (1.f - lh) * (1.f - lw) : 0.f;
                c01[m] = (hv0 && wv1) ? (1.f - lh) * lw : 0.f;
                c10[m] = (hv1 && wv0) ? lh * (1.f - lw) : 0.f;
                c11[m] = (hv1 && wv1) ? lh * lw : 0.f;
                const int h0c = min(max(h0, 0), HH - 1);
                const int h1c = min(max(h0 + 1, 0), HH - 1);
                const int w0c = min(max(w0, 0), WW - 1);
                const int w1c = min(max(w0 + 1, 0), WW - 1);
                i00[m] = h0c * WW + w0c;
                i01[m] = h0c * WW + w1c;
                i10[m] = h1c * WW + w0c;
                i11[m] = h1c * WW + w1c;
            }
            // batch 2: gathers + blend + MFMA
#pragma unroll
            for (int m = 0; m < 4; m++) {
                F16Frag a00, a01, a10, a11, A;
                a00.v = *(const f16x8*)(xd + (size_t)i00[m] * CC + kg * 8);
                a01.v = *(const f16x8*)(xd + (size_t)i01[m] * CC + kg * 8);
                a10.v = *(const f16x8*)(xd + (size_t)i10[m] * CC + kg * 8);
                a11.v = *(const f16x8*)(xd + (size_t)i11[m] * CC + kg * 8);
                const __half2 C00 = __float2half2_rn(c00[m]);
                const __half2 C01 = __float2half2_rn(c01[m]);
                const __half2 C10 = __float2half2_rn(c10[m]);
                const __half2 C11 = __float2half2_rn(c11[m]);
#pragma unroll
                for (int r = 0; r < 4; r++) {
                    __half2 t = __hmul2(C00, a00.h2[r]);
                    t = __hfma2(C01, a01.h2[r], t);
                    t = __hfma2(C10, a10.h2[r], t);
                    t = __hfma2(C11, a11.h2[r], t);
                    A.h2[r] = t;
                }
                acd[m][0] = __builtin_amdgcn_mfma_f32_16x16x32_f16(A.v, b0, acd[m][0], 0, 0, 0);
                acd[m][1] = __builtin_amdgcn_mfma_f32_16x16x32_f16(A.v, b1, acd[m][1], 0, 0, 0);
            }
        }
    }
    __syncthreads();   // offsets dead; reuse LDS for output staging

    // ================= Phase D: stage + coalesced copy-out =================
#pragma unroll
    for (int m = 0; m < 4; m++)
#pragma unroll
        for (int nt = 0; nt < 2; nt++) {
            const int o = nt * 16 + mrow;
            *(f32x4*)&out_lds[o * 132 + wave * 64 + m * 16 + kg * 4] = acd[m][nt];
        }
    __syncthreads();
    if (resid) {
#pragma unroll 1
        for (int o = 0; o < CC; o++) {
            float v = out_lds[o * 132 + tid] + db[o] + resid[(size_t)o * DHW + p0 + tid];
            outp[(size_t)o * DHW + p0 + tid] = v;
        }
    } else {
#pragma unroll 1
        for (int o = 0; o < CC; o++)
            outp[(size_t)o * DHW + p0 + tid] = out_lds[o * 132 + tid] + db[o];
    }
}

extern "C" void kernel_launch(void* const* d_in, const int* in_sizes, int n_in,
                              void* d_out, int out_size, void* d_ws, size_t ws_size,
                              hipStream_t stream) {
    const float* x   = (const float*)d_in[0];
    const float* g1  = (const float*)d_in[1];
    const float* be1 = (const float*)d_in[2];
    const float* g2  = (const float*)d_in[3];
    const float* be2 = (const float*)d_in[4];
    const float* ow1 = (const float*)d_in[5];
    const float* ob1 = (const float*)d_in[6];
    const float* dw1 = (const float*)d_in[7];
    const float* db1 = (const float*)d_in[8];
    const float* ow2 = (const float*)d_in[9];
    const float* ob2 = (const float*)d_in[10];
    const float* dw2 = (const float*)d_in[11];
    const float* db2 = (const float*)d_in[12];
    float* out = (float*)d_out;
    float* ws  = (float*)d_ws;

    // ws layout (float offsets)
    float*    stats = ws;                           // 16
    _Float16* wBo1  = (_Float16*)(ws + 256);        // 55296 h = 27648 f
    _Float16* wBd1  = (_Float16*)(ws + 27904);      // 27648 h = 13824 f
    _Float16* wBo2  = (_Float16*)(ws + 41728);      // 27648 f
    _Float16* wBd2  = (_Float16*)(ws + 69376);      // 13824 f
    __half*   hT    = (__half*)(ws + 83200);        // DHW*32 h = 3538944 f

    (void)hipMemsetAsync(stats, 0, 16 * sizeof(float), stream);
    pack_w<<<(27 * 4 * 512 + 255) / 256, 256, 0, stream>>>(ow1, wBo1, 54, 4, 27 * 4 * 512);
    pack_w<<<(27 * 2 * 512 + 255) / 256, 256, 0, stream>>>(dw1, wBd1, 32, 2, 27 * 2 * 512);
    pack_w<<<(27 * 4 * 512 + 255) / 256, 256, 0, stream>>>(ow2, wBo2, 54, 4, 27 * 4 * 512);
    pack_w<<<(27 * 2 * 512 + 255) / 256, 256, 0, stream>>>(dw2, wBd2, 32, 2, 27 * 2 * 512);

    // block 1
    gn_stats<<<NG * 32, 256, 0, stream>>>(x, stats + 0);
    gn_apply_T<<<NBLK_G, 256, 0, stream>>>(x, stats + 0, g1, be1, hT);
    fused_conv<<<NBLK_F, 128, 0, stream>>>(hT, wBo1, ob1, wBd1, db1, nullptr, out);

    // block 2 (input = block-1 output in d_out)
    gn_stats<<<NG * 32, 256, 0, stream>>>(out, stats + 8);
    gn_apply_T<<<NBLK_G, 256, 0, stream>>>(out, stats + 8, g2, be2, hT);
    fused_conv<<<NBLK_F, 128, 0, stream>>>(hT, wBo2, ob2, wBd2, db2, x, out);
}